// Round 4
// baseline (310.824 us; speedup 1.0000x reference)
//
#include <hip/hip_runtime.h>
#include <hip/hip_bf16.h>

#define DM    768
#define HEADS 12
#define DK    64
#define SEQ   2048
#define BATCH 4
#define NE    ((size_t)BATCH * SEQ * DM)   // 6,291,456

typedef short v8s __attribute__((ext_vector_type(8)));
typedef float v4f __attribute__((ext_vector_type(4)));

#define LDS_PTR(p) ((__attribute__((address_space(3))) unsigned int*)(p))
#define GLB_PTR(p) ((const __attribute__((address_space(1))) unsigned int*)(p))

__device__ __forceinline__ unsigned short f2bf(float f) {
    union { float f; unsigned u; } v; v.f = f;
    unsigned r = (v.u + 0x7FFFu + ((v.u >> 16) & 1u)) >> 16;
    return (unsigned short)r;
}

// ---------------------------------------------------------------------------
// x fp32 -> bf16, flat. 8 elems/thread.
// ---------------------------------------------------------------------------
__global__ __launch_bounds__(256)
void cvt_x_kernel(const float* __restrict__ x, unsigned short* __restrict__ xb) {
    const size_t i = ((size_t)blockIdx.x * 256 + threadIdx.x) * 8;
    const float4 a = *(const float4*)(x + i);
    const float4 b = *(const float4*)(x + i + 4);
    v8s o;
    o[0] = (short)f2bf(a.x); o[1] = (short)f2bf(a.y);
    o[2] = (short)f2bf(a.z); o[3] = (short)f2bf(a.w);
    o[4] = (short)f2bf(b.x); o[5] = (short)f2bf(b.y);
    o[6] = (short)f2bf(b.z); o[7] = (short)f2bf(b.w);
    *(v8s*)(xb + i) = o;
}

// ---------------------------------------------------------------------------
// W[k][n] fp32 -> WT[n][k] bf16 (64x64 LDS transpose). z selects weight.
// z==0 (Wq) additionally scaled by 1/8.
// ---------------------------------------------------------------------------
__global__ __launch_bounds__(256)
void cvt_w_kernel(const float* __restrict__ W0, const float* __restrict__ W1,
                  const float* __restrict__ W2, const float* __restrict__ W3,
                  unsigned short* __restrict__ wt) {
    __shared__ unsigned short T[64][72];
    const int z = blockIdx.z;
    const float* W = (z == 0) ? W0 : (z == 1) ? W1 : (z == 2) ? W2 : W3;
    const float scale = (z == 0) ? 0.125f : 1.0f;
    unsigned short* dst = wt + (size_t)z * DM * DM;
    const int k0 = blockIdx.x * 64, n0 = blockIdx.y * 64;
    const int t = threadIdx.x;
    {
        const int kr = t >> 2;
        const int ns = (t & 3) * 16;
        #pragma unroll
        for (int j = 0; j < 4; ++j) {
            const float4 v = *(const float4*)(W + (size_t)(k0 + kr) * DM + n0 + ns + j * 4);
            T[ns + j * 4 + 0][kr] = f2bf(v.x * scale);
            T[ns + j * 4 + 1][kr] = f2bf(v.y * scale);
            T[ns + j * 4 + 2][kr] = f2bf(v.z * scale);
            T[ns + j * 4 + 3][kr] = f2bf(v.w * scale);
        }
    }
    __syncthreads();
    {
        const int n = t >> 2;
        const int ks = (t & 3) * 16;
        #pragma unroll
        for (int j = 0; j < 2; ++j)
            *(v8s*)(dst + (size_t)(n0 + n) * DM + k0 + ks + j * 8) = *(const v8s*)&T[n][ks + j * 8];
    }
}

// ---------------------------------------------------------------------------
// m97-style GEMM core macro-structure (shared by qkv and out kernels):
// 128x128 tile, BK=64, global_load_lds 16B staging, frag-major LDS.
// LDS chunk c (0..127 per matrix) holds 64 lanes x 16B; chunk index
// (rf*2 + kc): rows rf*16+l15, cols kc*32+quad*8. Block = 4 waves (2x2).
// ---------------------------------------------------------------------------

// QKV GEMM: z=0 -> Q[bh][s][d] (pre-scaled), z=1 -> K[bh][s][d], z=2 -> VT[bh][d][s]
__global__ __launch_bounds__(256)
void gemm_qkv_kernel(const unsigned short* __restrict__ xb, const unsigned short* __restrict__ wtbuf,
                     const float* __restrict__ bq, const float* __restrict__ bk,
                     const float* __restrict__ bv,
                     unsigned short* __restrict__ qb, unsigned short* __restrict__ kb,
                     unsigned short* __restrict__ vtb) {
    __shared__ unsigned short smem[16384];        // As 8192 | Bs 8192 (shorts)
    unsigned short* As = smem;
    unsigned short* Bs = smem + 8192;
    const int z = blockIdx.z;
    const unsigned short* wt = wtbuf + (size_t)z * DM * DM;
    const float* bias = (z == 0) ? bq : (z == 1) ? bk : bv;
    const float bscale = (z == 0) ? 0.125f : 1.0f;

    const int t = threadIdx.x;
    const int w = t >> 6, lane = t & 63, quad = lane >> 4, l15 = lane & 15;
    const int wm = w >> 1, wn = w & 1;
    const int M0 = blockIdx.x * 128;
    const int N0 = blockIdx.y * 128;

    v4f acc[4][4];
    #pragma unroll
    for (int i = 0; i < 4; ++i)
        #pragma unroll
        for (int j = 0; j < 4; ++j) acc[i][j] = (v4f){0, 0, 0, 0};

    for (int k0 = 0; k0 < DM; k0 += 64) {
        __syncthreads();   // prev-iter readers done
        #pragma unroll
        for (int u = 0; u < 2; ++u) {
            const int rf = w * 2 + u;    // 0..7
            #pragma unroll
            for (int kc = 0; kc < 2; ++kc) {
                const unsigned short* ga = xb + (size_t)(M0 + rf * 16 + l15) * DM + k0 + kc * 32 + quad * 8;
                __builtin_amdgcn_global_load_lds(GLB_PTR(ga), LDS_PTR(As + ((rf * 2 + kc) * 64) * 8), 16, 0, 0);
                const unsigned short* gb = wt + (size_t)(N0 + rf * 16 + l15) * DM + k0 + kc * 32 + quad * 8;
                __builtin_amdgcn_global_load_lds(GLB_PTR(gb), LDS_PTR(Bs + ((rf * 2 + kc) * 64) * 8), 16, 0, 0);
            }
        }
        __syncthreads();   // vmcnt(0) drain -> staged data visible
        #pragma unroll
        for (int kc = 0; kc < 2; ++kc) {
            v8s a[4], b[4];
            #pragma unroll
            for (int i = 0; i < 4; ++i)
                a[i] = *(const v8s*)&As[(((wm * 4 + i) * 2 + kc) * 64 + lane) * 8];
            #pragma unroll
            for (int j = 0; j < 4; ++j)
                b[j] = *(const v8s*)&Bs[(((wn * 4 + j) * 2 + kc) * 64 + lane) * 8];
            #pragma unroll
            for (int i = 0; i < 4; ++i)
                #pragma unroll
                for (int j = 0; j < 4; ++j)
                    acc[i][j] = __builtin_amdgcn_mfma_f32_16x16x32_bf16(a[i], b[j], acc[i][j], 0, 0, 0);
        }
    }

    const int b_ = M0 >> 11;                       // batch (128-row tile never straddles)
    const int sidx0 = M0 & 2047;
    const int h0 = N0 >> 6;                        // first of 2 heads in this n-tile

    if (z < 2) {   // Q/K: [bh][s][64]
        unsigned short* outp = (z == 0) ? qb : kb;
        #pragma unroll
        for (int j = 0; j < 4; ++j) {
            const int n = N0 + wn * 64 + j * 16 + l15;
            const int h = n >> 6, d = n & 63;
            const float bv_ = bias[n] * bscale;
            #pragma unroll
            for (int i = 0; i < 4; ++i)
                #pragma unroll
                for (int r = 0; r < 4; ++r) {
                    const int sidx = sidx0 + wm * 64 + i * 16 + quad * 4 + r;
                    outp[(((size_t)(b_ * HEADS + h) * SEQ + sidx) << 6) + d] = f2bf(acc[i][j][r] + bv_);
                }
        }
    } else {       // V -> VT[bh][d][s], two m-half phases through LDS
        unsigned short* Ts = smem;                 // [128 dloc][72] (m-half 64 + pad)
        #pragma unroll
        for (int p = 0; p < 2; ++p) {
            __syncthreads();
            if (wm == p) {
                #pragma unroll
                for (int j = 0; j < 4; ++j) {
                    const int dloc = wn * 64 + j * 16 + l15;
                    const float bv_ = bias[N0 + dloc];
                    #pragma unroll
                    for (int i = 0; i < 4; ++i)
                        #pragma unroll
                        for (int r = 0; r < 4; ++r)
                            Ts[dloc * 72 + i * 16 + quad * 4 + r] = f2bf(acc[i][j][r] + bv_);
                }
            }
            __syncthreads();
            const int dloc = t >> 1, ms = (t & 1) * 32;
            const int h = h0 + (dloc >> 6), d = dloc & 63;
            unsigned short* dst = vtb + (((size_t)(b_ * HEADS + h) * DK + d) << 11) + sidx0 + p * 64 + ms;
            #pragma unroll
            for (int jj = 0; jj < 4; ++jj)
                *(v8s*)(dst + jj * 8) = *(const v8s*)&Ts[dloc * 72 + ms + jj * 8];
        }
    }
}

// Output projection: out fp32 [8192][768] = ob(bf16) @ WoT^T + bo
__global__ __launch_bounds__(256)
void gemm_out_kernel(const unsigned short* __restrict__ ob, const unsigned short* __restrict__ wto,
                     const float* __restrict__ bias, float* __restrict__ out) {
    __shared__ unsigned short smem[16384];
    unsigned short* As = smem;
    unsigned short* Bs = smem + 8192;
    const int t = threadIdx.x;
    const int w = t >> 6, lane = t & 63, quad = lane >> 4, l15 = lane & 15;
    const int wm = w >> 1, wn = w & 1;
    const int M0 = blockIdx.x * 128;
    const int N0 = blockIdx.y * 128;

    v4f acc[4][4];
    #pragma unroll
    for (int i = 0; i < 4; ++i)
        #pragma unroll
        for (int j = 0; j < 4; ++j) acc[i][j] = (v4f){0, 0, 0, 0};

    for (int k0 = 0; k0 < DM; k0 += 64) {
        __syncthreads();
        #pragma unroll
        for (int u = 0; u < 2; ++u) {
            const int rf = w * 2 + u;
            #pragma unroll
            for (int kc = 0; kc < 2; ++kc) {
                const unsigned short* ga = ob + (size_t)(M0 + rf * 16 + l15) * DM + k0 + kc * 32 + quad * 8;
                __builtin_amdgcn_global_load_lds(GLB_PTR(ga), LDS_PTR(As + ((rf * 2 + kc) * 64) * 8), 16, 0, 0);
                const unsigned short* gb = wto + (size_t)(N0 + rf * 16 + l15) * DM + k0 + kc * 32 + quad * 8;
                __builtin_amdgcn_global_load_lds(GLB_PTR(gb), LDS_PTR(Bs + ((rf * 2 + kc) * 64) * 8), 16, 0, 0);
            }
        }
        __syncthreads();
        #pragma unroll
        for (int kc = 0; kc < 2; ++kc) {
            v8s a[4], b[4];
            #pragma unroll
            for (int i = 0; i < 4; ++i)
                a[i] = *(const v8s*)&As[(((wm * 4 + i) * 2 + kc) * 64 + lane) * 8];
            #pragma unroll
            for (int j = 0; j < 4; ++j)
                b[j] = *(const v8s*)&Bs[(((wn * 4 + j) * 2 + kc) * 64 + lane) * 8];
            #pragma unroll
            for (int i = 0; i < 4; ++i)
                #pragma unroll
                for (int j = 0; j < 4; ++j)
                    acc[i][j] = __builtin_amdgcn_mfma_f32_16x16x32_bf16(a[i], b[j], acc[i][j], 0, 0, 0);
        }
    }

    #pragma unroll
    for (int j = 0; j < 4; ++j) {
        const int n = N0 + wn * 64 + j * 16 + l15;
        const float bv_ = bias[n];
        #pragma unroll
        for (int i = 0; i < 4; ++i)
            #pragma unroll
            for (int r = 0; r < 4; ++r) {
                const int m = M0 + wm * 64 + i * 16 + quad * 4 + r;
                out[(size_t)m * DM + n] = acc[i][j][r] + bv_;
            }
    }
}

// ---------------------------------------------------------------------------
// Causal flash attention, single-buffered LDS K/V (36.9 KB -> 4 blocks/CU).
// grid 768 = 48 bh x 16 strips(128 q-rows) descending; block 256 = 4 waves.
// Register prefetch of next tile spans the two barriers.
// ---------------------------------------------------------------------------
__global__ __launch_bounds__(256)
void attn_kernel(const unsigned short* __restrict__ Q, const unsigned short* __restrict__ K,
                 const unsigned short* __restrict__ VT, unsigned short* __restrict__ O) {
    __shared__ unsigned short Kb[64][72];      // [key][dk]
    __shared__ unsigned short Vb[64][72];      // [dk][key]
    __shared__ unsigned short Ps[4][32][72];   // per-wave P round-trip
    const int t = threadIdx.x;
    const int w = t >> 6, lane = t & 63, quad = lane >> 4, l15 = lane & 15;

    const int idx = blockIdx.x;
    const int xcd = idx & 7;
    const int j   = idx >> 3;                  // 0..95
    const int bh  = xcd + 8 * (j >> 4);        // 0..47
    const int qt  = 15 - (j & 15);             // descending work size
    const int q0  = qt * 128;
    const int nkt = 2 * qt + 2;
    const size_t kvbase = (size_t)bh * SEQ * DK;

    v8s qf[2][2];
    #pragma unroll
    for (int mf = 0; mf < 2; ++mf)
        #pragma unroll
        for (int c = 0; c < 2; ++c)
            qf[mf][c] = *(const v8s*)(Q + kvbase + (size_t)(q0 + w * 32 + mf * 16 + l15) * DK + c * 32 + quad * 8);

    v4f o[2][4];
    #pragma unroll
    for (int mf = 0; mf < 2; ++mf)
        #pragma unroll
        for (int nf = 0; nf < 4; ++nf) o[mf][nf] = (v4f){0, 0, 0, 0};
    float lsum[2][4] = { {0,0,0,0}, {0,0,0,0} };

    const int srow = t >> 3;          // 0..31
    const int scol = (t & 7) * 8;     // 0..56

    // preload tile 0
    v8s kr0 = *(const v8s*)(K  + kvbase + (size_t)srow * DK + scol);
    v8s kr1 = *(const v8s*)(K  + kvbase + (size_t)(srow + 32) * DK + scol);
    v8s vr0 = *(const v8s*)(VT + kvbase + ((size_t)srow << 11) + scol);
    v8s vr1 = *(const v8s*)(VT + kvbase + ((size_t)(srow + 32) << 11) + scol);
    *(v8s*)&Kb[srow][scol]      = kr0;
    *(v8s*)&Kb[srow + 32][scol] = kr1;
    *(v8s*)&Vb[srow][scol]      = vr0;
    *(v8s*)&Vb[srow + 32][scol] = vr1;
    __syncthreads();

    const int rowb = q0 + w * 32;

    for (int kt = 0; kt < nkt; ++kt) {
        const int k0 = kt * 64;
        // prefetch next tile into regs (global loads overlap compute)
        if (kt + 1 < nkt) {
            const int kn = k0 + 64;
            kr0 = *(const v8s*)(K  + kvbase + (size_t)(kn + srow) * DK + scol);
            kr1 = *(const v8s*)(K  + kvbase + (size_t)(kn + srow + 32) * DK + scol);
            vr0 = *(const v8s*)(VT + kvbase + ((size_t)srow << 11) + kn + scol);
            vr1 = *(const v8s*)(VT + kvbase + ((size_t)(srow + 32) << 11) + kn + scol);
        }

        // QK
        v4f sc[2][4];
        #pragma unroll
        for (int mf = 0; mf < 2; ++mf)
            #pragma unroll
            for (int s = 0; s < 4; ++s) sc[mf][s] = (v4f){0, 0, 0, 0};
        #pragma unroll
        for (int c = 0; c < 2; ++c)
            #pragma unroll
            for (int s = 0; s < 4; ++s) {
                const v8s kf = *(const v8s*)&Kb[s * 16 + l15][c * 32 + quad * 8];
                #pragma unroll
                for (int mf = 0; mf < 2; ++mf)
                    sc[mf][s] = __builtin_amdgcn_mfma_f32_16x16x32_bf16(qf[mf][c], kf, sc[mf][s], 0, 0, 0);
            }

        // exp (+ causal mask on last two tiles)
        if (kt < nkt - 2) {
            #pragma unroll
            for (int mf = 0; mf < 2; ++mf)
                #pragma unroll
                for (int s = 0; s < 4; ++s)
                    #pragma unroll
                    for (int r = 0; r < 4; ++r) {
                        const float p = __expf(sc[mf][s][r]);
                        lsum[mf][r] += p;
                        Ps[w][mf * 16 + quad * 4 + r][s * 16 + l15] = f2bf(p);
                    }
        } else {
            #pragma unroll
            for (int mf = 0; mf < 2; ++mf)
                #pragma unroll
                for (int s = 0; s < 4; ++s) {
                    const int key = k0 + s * 16 + l15;
                    #pragma unroll
                    for (int r = 0; r < 4; ++r) {
                        const int row = rowb + mf * 16 + quad * 4 + r;
                        const float p = (key <= row) ? __expf(sc[mf][s][r]) : 0.f;
                        lsum[mf][r] += p;
                        Ps[w][mf * 16 + quad * 4 + r][s * 16 + l15] = f2bf(p);
                    }
                }
        }

        // PV
        #pragma unroll
        for (int kc = 0; kc < 2; ++kc) {
            v8s pf[2];
            #pragma unroll
            for (int mf = 0; mf < 2; ++mf)
                pf[mf] = *(const v8s*)&Ps[w][mf * 16 + l15][kc * 32 + quad * 8];
            #pragma unroll
            for (int nf = 0; nf < 4; ++nf) {
                const v8s vf = *(const v8s*)&Vb[nf * 16 + l15][kc * 32 + quad * 8];
                #pragma unroll
                for (int mf = 0; mf < 2; ++mf)
                    o[mf][nf] = __builtin_amdgcn_mfma_f32_16x16x32_bf16(pf[mf], vf, o[mf][nf], 0, 0, 0);
            }
        }

        __syncthreads();   // all waves done reading Kb/Vb for tile kt
        if (kt + 1 < nkt) {
            *(v8s*)&Kb[srow][scol]      = kr0;
            *(v8s*)&Kb[srow + 32][scol] = kr1;
            *(v8s*)&Vb[srow][scol]      = vr0;
            *(v8s*)&Vb[srow + 32][scol] = vr1;
        }
        __syncthreads();   // staged tile kt+1 visible
    }

    #pragma unroll
    for (int off = 1; off < 16; off <<= 1)
        #pragma unroll
        for (int mf = 0; mf < 2; ++mf)
            #pragma unroll
            for (int r = 0; r < 4; ++r) lsum[mf][r] += __shfl_xor(lsum[mf][r], off);

    const int b = bh / HEADS, h = bh % HEADS;
    #pragma unroll
    for (int mf = 0; mf < 2; ++mf)
        #pragma unroll
        for (int r = 0; r < 4; ++r) {
            const float inv = 1.f / lsum[mf][r];
            const int row = rowb + mf * 16 + quad * 4 + r;
            const size_t rowoff = ((size_t)b * SEQ + row) * DM + h * DK;
            #pragma unroll
            for (int nf = 0; nf < 4; ++nf)
                O[rowoff + nf * 16 + l15] = f2bf(o[mf][nf][r] * inv);
        }
}

extern "C" void kernel_launch(void* const* d_in, const int* in_sizes, int n_in,
                              void* d_out, int out_size, void* d_ws, size_t ws_size,
                              hipStream_t stream) {
    const float* x  = (const float*)d_in[0];
    const float* Wq = (const float*)d_in[1];
    const float* bq = (const float*)d_in[2];
    const float* Wk = (const float*)d_in[3];
    const float* bk = (const float*)d_in[4];
    const float* Wv = (const float*)d_in[5];
    const float* bv = (const float*)d_in[6];
    const float* Wo = (const float*)d_in[7];
    const float* bo = (const float*)d_in[8];
    float* out = (float*)d_out;

    unsigned short* xb  = (unsigned short*)d_ws;      // [8192][768] bf16; reused as ob
    unsigned short* qb  = xb  + NE;                   // [bh][s][64]
    unsigned short* kb  = qb  + NE;                   // [bh][s][64]
    unsigned short* vtb = kb  + NE;                   // [bh][64][s]
    unsigned short* wt  = vtb + NE;                   // 4 x [768][768] bf16 (q,k,v,o), transposed
    unsigned short* ob  = xb;                         // alias (xb dead after gemm_qkv)

    cvt_x_kernel<<<dim3(NE / (8 * 256)), 256, 0, stream>>>(x, xb);
    cvt_w_kernel<<<dim3(12, 12, 4), 256, 0, stream>>>(Wq, Wk, Wv, Wo, wt);
    gemm_qkv_kernel<<<dim3(64, 6, 3), 256, 0, stream>>>(xb, wt, bq, bk, bv, qb, kb, vtb);
    attn_kernel<<<dim3(768), 256, 0, stream>>>(qb, kb, vtb, ob);
    gemm_out_kernel<<<dim3(64, 6), 256, 0, stream>>>(ob, wt + (size_t)3 * DM * DM, bo, out);
}

// Round 5
// 245.406 us; speedup vs baseline: 1.2666x; 1.2666x over previous
//
#include <hip/hip_runtime.h>
#include <hip/hip_bf16.h>

#define DM    768
#define HEADS 12
#define DK    64
#define SEQ   2048
#define BATCH 4
#define NE    ((size_t)BATCH * SEQ * DM)   // 6,291,456
#define KT    12                           // 768/64 k-tiles per row-block
#define BRICK 8192                         // 128 rows x 64 k shorts per tile

typedef short v8s __attribute__((ext_vector_type(8)));
typedef float v4f __attribute__((ext_vector_type(4)));

#define LDS_PTR(p) ((__attribute__((address_space(3))) unsigned int*)(p))
#define GLB_PTR(p) ((const __attribute__((address_space(1))) unsigned int*)(p))

__device__ __forceinline__ unsigned short f2bf(float f) {
    union { float f; unsigned u; } v; v.f = f;
    unsigned r = (v.u + 0x7FFFu + ((v.u >> 16) & 1u)) >> 16;
    return (unsigned short)r;
}

// ---------------------------------------------------------------------------
// x fp32 -> bf16, written TILED: [(m>>7)*12 + (k>>6)][m&127][k&63]
// ---------------------------------------------------------------------------
__global__ __launch_bounds__(256)
void cvt_x_kernel(const float* __restrict__ x, unsigned short* __restrict__ xb) {
    const size_t p = ((size_t)blockIdx.x * 256 + threadIdx.x) * 8;
    const int m = (int)(p / DM);
    const int k = (int)(p % DM);
    const float4 a = *(const float4*)(x + p);
    const float4 b = *(const float4*)(x + p + 4);
    v8s o;
    o[0] = (short)f2bf(a.x); o[1] = (short)f2bf(a.y);
    o[2] = (short)f2bf(a.z); o[3] = (short)f2bf(a.w);
    o[4] = (short)f2bf(b.x); o[5] = (short)f2bf(b.y);
    o[6] = (short)f2bf(b.z); o[7] = (short)f2bf(b.w);
    const size_t dst = ((size_t)(m >> 7) * KT + (k >> 6)) * BRICK + (size_t)(m & 127) * 64 + (k & 63);
    *(v8s*)(xb + dst) = o;
}

// ---------------------------------------------------------------------------
// W[k][n] fp32 -> WT tiled: [(n>>7)*12 + (k>>6)][n&127][k&63] bf16.
// z==0 (Wq) scaled by 1/8.
// ---------------------------------------------------------------------------
__global__ __launch_bounds__(256)
void cvt_w_kernel(const float* __restrict__ W0, const float* __restrict__ W1,
                  const float* __restrict__ W2, const float* __restrict__ W3,
                  unsigned short* __restrict__ wt) {
    __shared__ unsigned short T[64][72];
    const int z = blockIdx.z;
    const float* W = (z == 0) ? W0 : (z == 1) ? W1 : (z == 2) ? W2 : W3;
    const float scale = (z == 0) ? 0.125f : 1.0f;
    const int k0 = blockIdx.x * 64, n0 = blockIdx.y * 64;
    const int t = threadIdx.x;
    {
        const int kr = t >> 2;
        const int ns = (t & 3) * 16;
        #pragma unroll
        for (int j = 0; j < 4; ++j) {
            const float4 v = *(const float4*)(W + (size_t)(k0 + kr) * DM + n0 + ns + j * 4);
            T[ns + j * 4 + 0][kr] = f2bf(v.x * scale);
            T[ns + j * 4 + 1][kr] = f2bf(v.y * scale);
            T[ns + j * 4 + 2][kr] = f2bf(v.z * scale);
            T[ns + j * 4 + 3][kr] = f2bf(v.w * scale);
        }
    }
    __syncthreads();
    {
        unsigned short* dst = wt + (size_t)z * DM * DM +
            ((size_t)(n0 >> 7) * KT + (k0 >> 6)) * BRICK + (size_t)(n0 & 64) * 64;
        const int n = t >> 2;
        const int ks = (t & 3) * 16;
        #pragma unroll
        for (int j = 0; j < 2; ++j)
            *(v8s*)(dst + (size_t)n * 64 + ks + j * 8) = *(const v8s*)&T[n][ks + j * 8];
    }
}

// ---------------------------------------------------------------------------
// GEMM core: 128x128 tile, BK=64, global_load_lds 16B from TILED operands.
// Window win (0..15) = 1 KB contiguous; XOR swizzle: global chunk
// (r=i>>3, c8=(i&7)^r) -> LDS slot i. Frag read: slot = r*8 + (c8^r).
// ---------------------------------------------------------------------------

// QKV GEMM: z=0 -> Q[bh][s][d] (pre-scaled), z=1 -> K[bh][s][d], z=2 -> VT[bh][d][s]
__global__ __launch_bounds__(256)
void gemm_qkv_kernel(const unsigned short* __restrict__ xb, const unsigned short* __restrict__ wtbuf,
                     const float* __restrict__ bq, const float* __restrict__ bk,
                     const float* __restrict__ bv,
                     unsigned short* __restrict__ qb, unsigned short* __restrict__ kb,
                     unsigned short* __restrict__ vtb) {
    __shared__ unsigned short smem[16384];        // As 8192 | Bs 8192
    unsigned short* As = smem;
    unsigned short* Bs = smem + 8192;
    const int z = blockIdx.z;
    const float* bias = (z == 0) ? bq : (z == 1) ? bk : bv;
    const float bscale = (z == 0) ? 0.125f : 1.0f;

    const int t = threadIdx.x;
    const int w = t >> 6, lane = t & 63, quad = lane >> 4, l15 = lane & 15;
    const int wm = w >> 1, wn = w & 1;
    const int M0 = blockIdx.x * 128;
    const int N0 = blockIdx.y * 128;

    const unsigned short* gA = xb + ((size_t)(M0 >> 7) * KT) * BRICK;
    const unsigned short* gB = wtbuf + (size_t)z * DM * DM + ((size_t)(N0 >> 7) * KT) * BRICK;

    // staging lane offset (shorts): row r8 of window, swizzled chunk c8
    const int r8 = lane >> 3;
    const int c8 = (lane & 7) ^ r8;
    const int goff = r8 * 64 + c8 * 8;
    // frag-read lane components
    const int rl = l15 & 7, rh = l15 >> 3;

    v4f acc[4][4];
    #pragma unroll
    for (int i = 0; i < 4; ++i)
        #pragma unroll
        for (int j = 0; j < 4; ++j) acc[i][j] = (v4f){0, 0, 0, 0};

    for (int kt = 0; kt < KT; ++kt) {
        const unsigned short* ta = gA + kt * BRICK;
        const unsigned short* tb = gB + kt * BRICK;
        __syncthreads();   // prev-iter readers done
        #pragma unroll
        for (int u = 0; u < 4; ++u) {
            const int win = w * 4 + u;
            __builtin_amdgcn_global_load_lds(GLB_PTR(ta + win * 512 + goff), LDS_PTR(As + win * 512), 16, 0, 0);
            __builtin_amdgcn_global_load_lds(GLB_PTR(tb + win * 512 + goff), LDS_PTR(Bs + win * 512), 16, 0, 0);
        }
        __syncthreads();   // staged data visible
        #pragma unroll
        for (int kc = 0; kc < 2; ++kc) {
            const int cs = ((kc << 2) | quad) ^ rl;
            v8s a[4], b[4];
            #pragma unroll
            for (int i = 0; i < 4; ++i)
                a[i] = *(const v8s*)&As[(wm * 8 + i * 2 + rh) * 512 + rl * 64 + cs * 8];
            #pragma unroll
            for (int j = 0; j < 4; ++j)
                b[j] = *(const v8s*)&Bs[(wn * 8 + j * 2 + rh) * 512 + rl * 64 + cs * 8];
            #pragma unroll
            for (int i = 0; i < 4; ++i)
                #pragma unroll
                for (int j = 0; j < 4; ++j)
                    acc[i][j] = __builtin_amdgcn_mfma_f32_16x16x32_bf16(a[i], b[j], acc[i][j], 0, 0, 0);
        }
    }

    const int b_ = M0 >> 11;
    const int sidx0 = M0 & 2047;
    const int h0 = N0 >> 6;

    if (z < 2) {   // Q/K: [bh][s][64]
        unsigned short* outp = (z == 0) ? qb : kb;
        #pragma unroll
        for (int j = 0; j < 4; ++j) {
            const int n = N0 + wn * 64 + j * 16 + l15;
            const int h = n >> 6, d = n & 63;
            const float bv_ = bias[n] * bscale;
            #pragma unroll
            for (int i = 0; i < 4; ++i)
                #pragma unroll
                for (int r = 0; r < 4; ++r) {
                    const int sidx = sidx0 + wm * 64 + i * 16 + quad * 4 + r;
                    outp[(((size_t)(b_ * HEADS + h) * SEQ + sidx) << 6) + d] = f2bf(acc[i][j][r] + bv_);
                }
        }
    } else {       // V -> VT[bh][d][s], two m-half phases through LDS
        unsigned short* Ts = smem;                 // [128 dloc][72]
        #pragma unroll
        for (int p = 0; p < 2; ++p) {
            __syncthreads();
            if (wm == p) {
                #pragma unroll
                for (int j = 0; j < 4; ++j) {
                    const int dloc = wn * 64 + j * 16 + l15;
                    const float bv_ = bias[N0 + dloc];
                    #pragma unroll
                    for (int i = 0; i < 4; ++i)
                        #pragma unroll
                        for (int r = 0; r < 4; ++r)
                            Ts[dloc * 72 + i * 16 + quad * 4 + r] = f2bf(acc[i][j][r] + bv_);
                }
            }
            __syncthreads();
            const int dloc = t >> 1, ms = (t & 1) * 32;
            const int h = h0 + (dloc >> 6), d = dloc & 63;
            unsigned short* dst = vtb + (((size_t)(b_ * HEADS + h) * DK + d) << 11) + sidx0 + p * 64 + ms;
            #pragma unroll
            for (int jj = 0; jj < 4; ++jj)
                *(v8s*)(dst + jj * 8) = *(const v8s*)&Ts[dloc * 72 + ms + jj * 8];
        }
    }
}

// Output projection: out fp32 [8192][768] = ob(tiled bf16) @ WoT + bo
__global__ __launch_bounds__(256)
void gemm_out_kernel(const unsigned short* __restrict__ ob, const unsigned short* __restrict__ wto,
                     const float* __restrict__ bias, float* __restrict__ out) {
    __shared__ unsigned short smem[16384];
    unsigned short* As = smem;
    unsigned short* Bs = smem + 8192;
    const int t = threadIdx.x;
    const int w = t >> 6, lane = t & 63, quad = lane >> 4, l15 = lane & 15;
    const int wm = w >> 1, wn = w & 1;
    const int M0 = blockIdx.x * 128;
    const int N0 = blockIdx.y * 128;

    const unsigned short* gA = ob + ((size_t)(M0 >> 7) * KT) * BRICK;
    const unsigned short* gB = wto + ((size_t)(N0 >> 7) * KT) * BRICK;

    const int r8 = lane >> 3;
    const int c8 = (lane & 7) ^ r8;
    const int goff = r8 * 64 + c8 * 8;
    const int rl = l15 & 7, rh = l15 >> 3;

    v4f acc[4][4];
    #pragma unroll
    for (int i = 0; i < 4; ++i)
        #pragma unroll
        for (int j = 0; j < 4; ++j) acc[i][j] = (v4f){0, 0, 0, 0};

    for (int kt = 0; kt < KT; ++kt) {
        const unsigned short* ta = gA + kt * BRICK;
        const unsigned short* tb = gB + kt * BRICK;
        __syncthreads();
        #pragma unroll
        for (int u = 0; u < 4; ++u) {
            const int win = w * 4 + u;
            __builtin_amdgcn_global_load_lds(GLB_PTR(ta + win * 512 + goff), LDS_PTR(As + win * 512), 16, 0, 0);
            __builtin_amdgcn_global_load_lds(GLB_PTR(tb + win * 512 + goff), LDS_PTR(Bs + win * 512), 16, 0, 0);
        }
        __syncthreads();
        #pragma unroll
        for (int kc = 0; kc < 2; ++kc) {
            const int cs = ((kc << 2) | quad) ^ rl;
            v8s a[4], b[4];
            #pragma unroll
            for (int i = 0; i < 4; ++i)
                a[i] = *(const v8s*)&As[(wm * 8 + i * 2 + rh) * 512 + rl * 64 + cs * 8];
            #pragma unroll
            for (int j = 0; j < 4; ++j)
                b[j] = *(const v8s*)&Bs[(wn * 8 + j * 2 + rh) * 512 + rl * 64 + cs * 8];
            #pragma unroll
            for (int i = 0; i < 4; ++i)
                #pragma unroll
                for (int j = 0; j < 4; ++j)
                    acc[i][j] = __builtin_amdgcn_mfma_f32_16x16x32_bf16(a[i], b[j], acc[i][j], 0, 0, 0);
        }
    }

    #pragma unroll
    for (int j = 0; j < 4; ++j) {
        const int n = N0 + wn * 64 + j * 16 + l15;
        const float bv_ = bias[n];
        #pragma unroll
        for (int i = 0; i < 4; ++i)
            #pragma unroll
            for (int r = 0; r < 4; ++r) {
                const int m = M0 + wm * 64 + i * 16 + quad * 4 + r;
                out[(size_t)m * DM + n] = acc[i][j][r] + bv_;
            }
    }
}

// ---------------------------------------------------------------------------
// Causal flash attention (round-3 structure, measured 87 us), LDS-staged K/V
// double-buffered; O written in TILED layout for gemm_out.
// grid 768 = 48 bh x 16 strips(128 q-rows) descending; block 256 = 4 waves.
// ---------------------------------------------------------------------------
__global__ __launch_bounds__(256)
void attn_kernel(const unsigned short* __restrict__ Q, const unsigned short* __restrict__ K,
                 const unsigned short* __restrict__ VT, unsigned short* __restrict__ O) {
    __shared__ unsigned short Kb[2][64][72];   // [buf][key][dk]
    __shared__ unsigned short Vb[2][64][72];   // [buf][dk][key]
    __shared__ unsigned short Ps[4][32][72];   // per-wave P round-trip
    const int t = threadIdx.x;
    const int w = t >> 6, lane = t & 63, quad = lane >> 4, l15 = lane & 15;

    const int idx = blockIdx.x;
    const int xcd = idx & 7;
    const int j   = idx >> 3;                  // 0..95
    const int bh  = xcd + 8 * (j >> 4);        // 0..47
    const int qt  = 15 - (j & 15);             // descending work size
    const int q0  = qt * 128;
    const int nkt = 2 * qt + 2;
    const size_t kvbase = (size_t)bh * SEQ * DK;

    v8s qf[2][2];
    #pragma unroll
    for (int mf = 0; mf < 2; ++mf)
        #pragma unroll
        for (int c = 0; c < 2; ++c)
            qf[mf][c] = *(const v8s*)(Q + kvbase + (size_t)(q0 + w * 32 + mf * 16 + l15) * DK + c * 32 + quad * 8);

    v4f o[2][4];
    #pragma unroll
    for (int mf = 0; mf < 2; ++mf)
        #pragma unroll
        for (int nf = 0; nf < 4; ++nf) o[mf][nf] = (v4f){0, 0, 0, 0};
    float lsum[2][4] = { {0,0,0,0}, {0,0,0,0} };

    const int srow = t >> 3;          // 0..31
    const int scol = (t & 7) * 8;     // 0..56

    v8s kr0 = *(const v8s*)(K  + kvbase + (size_t)srow * DK + scol);
    v8s kr1 = *(const v8s*)(K  + kvbase + (size_t)(srow + 32) * DK + scol);
    v8s vr0 = *(const v8s*)(VT + kvbase + ((size_t)srow << 11) + scol);
    v8s vr1 = *(const v8s*)(VT + kvbase + ((size_t)(srow + 32) << 11) + scol);
    *(v8s*)&Kb[0][srow][scol]      = kr0;
    *(v8s*)&Kb[0][srow + 32][scol] = kr1;
    *(v8s*)&Vb[0][srow][scol]      = vr0;
    *(v8s*)&Vb[0][srow + 32][scol] = vr1;
    __syncthreads();

    const int rowb = q0 + w * 32;

    for (int kt = 0; kt < nkt; ++kt) {
        const int k0 = kt * 64;
        const int cur = kt & 1;
        if (kt + 1 < nkt) {
            const int kn = k0 + 64;
            kr0 = *(const v8s*)(K  + kvbase + (size_t)(kn + srow) * DK + scol);
            kr1 = *(const v8s*)(K  + kvbase + (size_t)(kn + srow + 32) * DK + scol);
            vr0 = *(const v8s*)(VT + kvbase + ((size_t)srow << 11) + kn + scol);
            vr1 = *(const v8s*)(VT + kvbase + ((size_t)(srow + 32) << 11) + kn + scol);
        }

        v4f sc[2][4];
        #pragma unroll
        for (int mf = 0; mf < 2; ++mf)
            #pragma unroll
            for (int s = 0; s < 4; ++s) sc[mf][s] = (v4f){0, 0, 0, 0};
        #pragma unroll
        for (int c = 0; c < 2; ++c)
            #pragma unroll
            for (int s = 0; s < 4; ++s) {
                const v8s kf = *(const v8s*)&Kb[cur][s * 16 + l15][c * 32 + quad * 8];
                #pragma unroll
                for (int mf = 0; mf < 2; ++mf)
                    sc[mf][s] = __builtin_amdgcn_mfma_f32_16x16x32_bf16(qf[mf][c], kf, sc[mf][s], 0, 0, 0);
            }

        if (kt < nkt - 2) {
            #pragma unroll
            for (int mf = 0; mf < 2; ++mf)
                #pragma unroll
                for (int s = 0; s < 4; ++s)
                    #pragma unroll
                    for (int r = 0; r < 4; ++r) {
                        const float p = __expf(sc[mf][s][r]);
                        lsum[mf][r] += p;
                        Ps[w][mf * 16 + quad * 4 + r][s * 16 + l15] = f2bf(p);
                    }
        } else {
            #pragma unroll
            for (int mf = 0; mf < 2; ++mf)
                #pragma unroll
                for (int s = 0; s < 4; ++s) {
                    const int key = k0 + s * 16 + l15;
                    #pragma unroll
                    for (int r = 0; r < 4; ++r) {
                        const int row = rowb + mf * 16 + quad * 4 + r;
                        const float p = (key <= row) ? __expf(sc[mf][s][r]) : 0.f;
                        lsum[mf][r] += p;
                        Ps[w][mf * 16 + quad * 4 + r][s * 16 + l15] = f2bf(p);
                    }
                }
        }

        #pragma unroll
        for (int kc = 0; kc < 2; ++kc) {
            v8s pf[2];
            #pragma unroll
            for (int mf = 0; mf < 2; ++mf)
                pf[mf] = *(const v8s*)&Ps[w][mf * 16 + l15][kc * 32 + quad * 8];
            #pragma unroll
            for (int nf = 0; nf < 4; ++nf) {
                const v8s vf = *(const v8s*)&Vb[cur][nf * 16 + l15][kc * 32 + quad * 8];
                #pragma unroll
                for (int mf = 0; mf < 2; ++mf)
                    o[mf][nf] = __builtin_amdgcn_mfma_f32_16x16x32_bf16(pf[mf], vf, o[mf][nf], 0, 0, 0);
            }
        }

        if (kt + 1 < nkt) {
            const int nxt = 1 - cur;
            *(v8s*)&Kb[nxt][srow][scol]      = kr0;
            *(v8s*)&Kb[nxt][srow + 32][scol] = kr1;
            *(v8s*)&Vb[nxt][srow][scol]      = vr0;
            *(v8s*)&Vb[nxt][srow + 32][scol] = vr1;
        }
        __syncthreads();
    }

    #pragma unroll
    for (int off = 1; off < 16; off <<= 1)
        #pragma unroll
        for (int mf = 0; mf < 2; ++mf)
            #pragma unroll
            for (int r = 0; r < 4; ++r) lsum[mf][r] += __shfl_xor(lsum[mf][r], off);

    // tiled O: brick ((b*16 + qt)*12 + h), row-local x 64
    const int b = bh / HEADS, h = bh % HEADS;
    const size_t obase = ((size_t)(b * 16 + qt) * KT + h) * BRICK;
    #pragma unroll
    for (int mf = 0; mf < 2; ++mf)
        #pragma unroll
        for (int r = 0; r < 4; ++r) {
            const float inv = 1.f / lsum[mf][r];
            const int rowl = w * 32 + mf * 16 + quad * 4 + r;
            #pragma unroll
            for (int nf = 0; nf < 4; ++nf)
                O[obase + (size_t)rowl * 64 + nf * 16 + l15] = f2bf(o[mf][nf][r] * inv);
        }
}

extern "C" void kernel_launch(void* const* d_in, const int* in_sizes, int n_in,
                              void* d_out, int out_size, void* d_ws, size_t ws_size,
                              hipStream_t stream) {
    const float* x  = (const float*)d_in[0];
    const float* Wq = (const float*)d_in[1];
    const float* bq = (const float*)d_in[2];
    const float* Wk = (const float*)d_in[3];
    const float* bk = (const float*)d_in[4];
    const float* Wv = (const float*)d_in[5];
    const float* bv = (const float*)d_in[6];
    const float* Wo = (const float*)d_in[7];
    const float* bo = (const float*)d_in[8];
    float* out = (float*)d_out;

    unsigned short* xb  = (unsigned short*)d_ws;      // tiled [8192][768] bf16; reused as ob
    unsigned short* qb  = xb  + NE;                   // [bh][s][64]
    unsigned short* kb  = qb  + NE;                   // [bh][s][64]
    unsigned short* vtb = kb  + NE;                   // [bh][64][s]
    unsigned short* wt  = vtb + NE;                   // 4 x [768][768] bf16 tiled (q,k,v,o)
    unsigned short* ob  = xb;                         // alias (xb dead after gemm_qkv)

    cvt_x_kernel<<<dim3(NE / (8 * 256)), 256, 0, stream>>>(x, xb);
    cvt_w_kernel<<<dim3(12, 12, 4), 256, 0, stream>>>(Wq, Wk, Wv, Wo, wt);
    gemm_qkv_kernel<<<dim3(64, 6, 3), 256, 0, stream>>>(xb, wt, bq, bk, bv, qb, kb, vtb);
    attn_kernel<<<dim3(768), 256, 0, stream>>>(qb, kb, vtb, ob);
    gemm_out_kernel<<<dim3(64, 6), 256, 0, stream>>>(ob, wt + (size_t)3 * DM * DM, bo, out);
}

// Round 6
// 221.449 us; speedup vs baseline: 1.4036x; 1.1082x over previous
//
#include <hip/hip_runtime.h>
#include <hip/hip_bf16.h>

#define DM    768
#define HEADS 12
#define DK    64
#define SEQ   2048
#define BATCH 4
#define NE    ((size_t)BATCH * SEQ * DM)   // 6,291,456
#define KT    12                           // 768/64 k-tiles per row-block
#define BRICK 8192                         // 128 rows x 64 k shorts per tile

typedef short v8s __attribute__((ext_vector_type(8)));
typedef float v4f __attribute__((ext_vector_type(4)));

#define LDS_PTR(p) ((__attribute__((address_space(3))) unsigned int*)(p))
#define GLB_PTR(p) ((const __attribute__((address_space(1))) unsigned int*)(p))

__device__ __forceinline__ unsigned short f2bf(float f) {
    union { float f; unsigned u; } v; v.f = f;
    unsigned r = (v.u + 0x7FFFu + ((v.u >> 16) & 1u)) >> 16;
    return (unsigned short)r;
}
__device__ __forceinline__ unsigned short f2bf_trunc(float f) {
    union { float f; unsigned u; } v; v.f = f;
    return (unsigned short)(v.u >> 16);
}

// ---------------------------------------------------------------------------
// x fp32 -> bf16, written TILED: [(m>>7)*12 + (k>>6)][m&127][k&63]
// ---------------------------------------------------------------------------
__global__ __launch_bounds__(256)
void cvt_x_kernel(const float* __restrict__ x, unsigned short* __restrict__ xb) {
    const size_t p = ((size_t)blockIdx.x * 256 + threadIdx.x) * 8;
    const int m = (int)(p / DM);
    const int k = (int)(p % DM);
    const float4 a = *(const float4*)(x + p);
    const float4 b = *(const float4*)(x + p + 4);
    v8s o;
    o[0] = (short)f2bf(a.x); o[1] = (short)f2bf(a.y);
    o[2] = (short)f2bf(a.z); o[3] = (short)f2bf(a.w);
    o[4] = (short)f2bf(b.x); o[5] = (short)f2bf(b.y);
    o[6] = (short)f2bf(b.z); o[7] = (short)f2bf(b.w);
    const size_t dst = ((size_t)(m >> 7) * KT + (k >> 6)) * BRICK + (size_t)(m & 127) * 64 + (k & 63);
    *(v8s*)(xb + dst) = o;
}

// ---------------------------------------------------------------------------
// W[k][n] fp32 -> WT tiled: [(n>>7)*12 + (k>>6)][n&127][k&63] bf16.
// z==0 (Wq) scaled by 1/8.
// ---------------------------------------------------------------------------
__global__ __launch_bounds__(256)
void cvt_w_kernel(const float* __restrict__ W0, const float* __restrict__ W1,
                  const float* __restrict__ W2, const float* __restrict__ W3,
                  unsigned short* __restrict__ wt) {
    __shared__ unsigned short T[64][72];
    const int z = blockIdx.z;
    const float* W = (z == 0) ? W0 : (z == 1) ? W1 : (z == 2) ? W2 : W3;
    const float scale = (z == 0) ? 0.125f : 1.0f;
    const int k0 = blockIdx.x * 64, n0 = blockIdx.y * 64;
    const int t = threadIdx.x;
    {
        const int kr = t >> 2;
        const int ns = (t & 3) * 16;
        #pragma unroll
        for (int j = 0; j < 4; ++j) {
            const float4 v = *(const float4*)(W + (size_t)(k0 + kr) * DM + n0 + ns + j * 4);
            T[ns + j * 4 + 0][kr] = f2bf(v.x * scale);
            T[ns + j * 4 + 1][kr] = f2bf(v.y * scale);
            T[ns + j * 4 + 2][kr] = f2bf(v.z * scale);
            T[ns + j * 4 + 3][kr] = f2bf(v.w * scale);
        }
    }
    __syncthreads();
    {
        unsigned short* dst = wt + (size_t)z * DM * DM +
            ((size_t)(n0 >> 7) * KT + (k0 >> 6)) * BRICK + (size_t)(n0 & 64) * 64;
        const int n = t >> 2;
        const int ks = (t & 3) * 16;
        #pragma unroll
        for (int j = 0; j < 2; ++j)
            *(v8s*)(dst + (size_t)n * 64 + ks + j * 8) = *(const v8s*)&T[n][ks + j * 8];
    }
}

// ---------------------------------------------------------------------------
// GEMM core: 128x128 tile, BK=64, global_load_lds 16B from TILED operands.
// XOR swizzle: global chunk (r=i>>3, c8=(i&7)^r) -> LDS slot i.
// ---------------------------------------------------------------------------

// QKV GEMM: z=0 -> Q[bh][s][d] (pre-scaled), z=1 -> K[bh][s][d], z=2 -> VT[bh][d][s]
__global__ __launch_bounds__(256)
void gemm_qkv_kernel(const unsigned short* __restrict__ xb, const unsigned short* __restrict__ wtbuf,
                     const float* __restrict__ bq, const float* __restrict__ bk,
                     const float* __restrict__ bv,
                     unsigned short* __restrict__ qb, unsigned short* __restrict__ kb,
                     unsigned short* __restrict__ vtb) {
    __shared__ unsigned short smem[16384];        // As 8192 | Bs 8192
    unsigned short* As = smem;
    unsigned short* Bs = smem + 8192;
    const int z = blockIdx.z;
    const float* bias = (z == 0) ? bq : (z == 1) ? bk : bv;
    const float bscale = (z == 0) ? 0.125f : 1.0f;

    const int t = threadIdx.x;
    const int w = t >> 6, lane = t & 63, quad = lane >> 4, l15 = lane & 15;
    const int wm = w >> 1, wn = w & 1;
    const int M0 = blockIdx.x * 128;
    const int N0 = blockIdx.y * 128;

    const unsigned short* gA = xb + ((size_t)(M0 >> 7) * KT) * BRICK;
    const unsigned short* gB = wtbuf + (size_t)z * DM * DM + ((size_t)(N0 >> 7) * KT) * BRICK;

    const int r8 = lane >> 3;
    const int c8 = (lane & 7) ^ r8;
    const int goff = r8 * 64 + c8 * 8;
    const int rl = l15 & 7, rh = l15 >> 3;

    v4f acc[4][4];
    #pragma unroll
    for (int i = 0; i < 4; ++i)
        #pragma unroll
        for (int j = 0; j < 4; ++j) acc[i][j] = (v4f){0, 0, 0, 0};

    for (int kt = 0; kt < KT; ++kt) {
        const unsigned short* ta = gA + kt * BRICK;
        const unsigned short* tb = gB + kt * BRICK;
        __syncthreads();
        #pragma unroll
        for (int u = 0; u < 4; ++u) {
            const int win = w * 4 + u;
            __builtin_amdgcn_global_load_lds(GLB_PTR(ta + win * 512 + goff), LDS_PTR(As + win * 512), 16, 0, 0);
            __builtin_amdgcn_global_load_lds(GLB_PTR(tb + win * 512 + goff), LDS_PTR(Bs + win * 512), 16, 0, 0);
        }
        __syncthreads();
        #pragma unroll
        for (int kc = 0; kc < 2; ++kc) {
            const int cs = ((kc << 2) | quad) ^ rl;
            v8s a[4], b[4];
            #pragma unroll
            for (int i = 0; i < 4; ++i)
                a[i] = *(const v8s*)&As[(wm * 8 + i * 2 + rh) * 512 + rl * 64 + cs * 8];
            #pragma unroll
            for (int j = 0; j < 4; ++j)
                b[j] = *(const v8s*)&Bs[(wn * 8 + j * 2 + rh) * 512 + rl * 64 + cs * 8];
            #pragma unroll
            for (int i = 0; i < 4; ++i)
                #pragma unroll
                for (int j = 0; j < 4; ++j)
                    acc[i][j] = __builtin_amdgcn_mfma_f32_16x16x32_bf16(a[i], b[j], acc[i][j], 0, 0, 0);
        }
    }

    const int b_ = M0 >> 11;
    const int sidx0 = M0 & 2047;
    const int h0 = N0 >> 6;

    if (z < 2) {   // Q/K: [bh][s][64]
        unsigned short* outp = (z == 0) ? qb : kb;
        #pragma unroll
        for (int j = 0; j < 4; ++j) {
            const int n = N0 + wn * 64 + j * 16 + l15;
            const int h = n >> 6, d = n & 63;
            const float bv_ = bias[n] * bscale;
            #pragma unroll
            for (int i = 0; i < 4; ++i)
                #pragma unroll
                for (int r = 0; r < 4; ++r) {
                    const int sidx = sidx0 + wm * 64 + i * 16 + quad * 4 + r;
                    outp[(((size_t)(b_ * HEADS + h) * SEQ + sidx) << 6) + d] = f2bf(acc[i][j][r] + bv_);
                }
        }
    } else {       // V -> VT[bh][d][s], two m-half phases through LDS
        unsigned short* Ts = smem;                 // [128 dloc][72]
        #pragma unroll
        for (int p = 0; p < 2; ++p) {
            __syncthreads();
            if (wm == p) {
                #pragma unroll
                for (int j = 0; j < 4; ++j) {
                    const int dloc = wn * 64 + j * 16 + l15;
                    const float bv_ = bias[N0 + dloc];
                    #pragma unroll
                    for (int i = 0; i < 4; ++i)
                        #pragma unroll
                        for (int r = 0; r < 4; ++r)
                            Ts[dloc * 72 + i * 16 + quad * 4 + r] = f2bf(acc[i][j][r] + bv_);
                }
            }
            __syncthreads();
            const int dloc = t >> 1, ms = (t & 1) * 32;
            const int h = h0 + (dloc >> 6), d = dloc & 63;
            unsigned short* dst = vtb + (((size_t)(b_ * HEADS + h) * DK + d) << 11) + sidx0 + p * 64 + ms;
            #pragma unroll
            for (int jj = 0; jj < 4; ++jj)
                *(v8s*)(dst + jj * 8) = *(const v8s*)&Ts[dloc * 72 + ms + jj * 8];
        }
    }
}

// Output projection: out fp32 [8192][768] = ob(tiled bf16) @ WoT + bo
__global__ __launch_bounds__(256)
void gemm_out_kernel(const unsigned short* __restrict__ ob, const unsigned short* __restrict__ wto,
                     const float* __restrict__ bias, float* __restrict__ out) {
    __shared__ unsigned short smem[16384];
    unsigned short* As = smem;
    unsigned short* Bs = smem + 8192;
    const int t = threadIdx.x;
    const int w = t >> 6, lane = t & 63, quad = lane >> 4, l15 = lane & 15;
    const int wm = w >> 1, wn = w & 1;
    const int M0 = blockIdx.x * 128;
    const int N0 = blockIdx.y * 128;

    const unsigned short* gA = ob + ((size_t)(M0 >> 7) * KT) * BRICK;
    const unsigned short* gB = wto + ((size_t)(N0 >> 7) * KT) * BRICK;

    const int r8 = lane >> 3;
    const int c8 = (lane & 7) ^ r8;
    const int goff = r8 * 64 + c8 * 8;
    const int rl = l15 & 7, rh = l15 >> 3;

    v4f acc[4][4];
    #pragma unroll
    for (int i = 0; i < 4; ++i)
        #pragma unroll
        for (int j = 0; j < 4; ++j) acc[i][j] = (v4f){0, 0, 0, 0};

    for (int kt = 0; kt < KT; ++kt) {
        const unsigned short* ta = gA + kt * BRICK;
        const unsigned short* tb = gB + kt * BRICK;
        __syncthreads();
        #pragma unroll
        for (int u = 0; u < 4; ++u) {
            const int win = w * 4 + u;
            __builtin_amdgcn_global_load_lds(GLB_PTR(ta + win * 512 + goff), LDS_PTR(As + win * 512), 16, 0, 0);
            __builtin_amdgcn_global_load_lds(GLB_PTR(tb + win * 512 + goff), LDS_PTR(Bs + win * 512), 16, 0, 0);
        }
        __syncthreads();
        #pragma unroll
        for (int kc = 0; kc < 2; ++kc) {
            const int cs = ((kc << 2) | quad) ^ rl;
            v8s a[4], b[4];
            #pragma unroll
            for (int i = 0; i < 4; ++i)
                a[i] = *(const v8s*)&As[(wm * 8 + i * 2 + rh) * 512 + rl * 64 + cs * 8];
            #pragma unroll
            for (int j = 0; j < 4; ++j)
                b[j] = *(const v8s*)&Bs[(wn * 8 + j * 2 + rh) * 512 + rl * 64 + cs * 8];
            #pragma unroll
            for (int i = 0; i < 4; ++i)
                #pragma unroll
                for (int j = 0; j < 4; ++j)
                    acc[i][j] = __builtin_amdgcn_mfma_f32_16x16x32_bf16(a[i], b[j], acc[i][j], 0, 0, 0);
        }
    }

    #pragma unroll
    for (int j = 0; j < 4; ++j) {
        const int n = N0 + wn * 64 + j * 16 + l15;
        const float bv_ = bias[n];
        #pragma unroll
        for (int i = 0; i < 4; ++i)
            #pragma unroll
            for (int r = 0; r < 4; ++r) {
                const int m = M0 + wm * 64 + i * 16 + quad * 4 + r;
                out[(size_t)m * DM + n] = acc[i][j][r] + bv_;
            }
    }
}

// ---------------------------------------------------------------------------
// Causal flash attention, pair-balanced strips.
// Block = (bh, pair s): strip A rows [64s, 64s+64), strip B rows [64(31-s), +64).
// One K-loop over tiles 0..31-s: B active every tile, A active while kt<=s.
// Uniform 33 tile-works per block; 768 uniform blocks = 3/CU (LDS 46.1 KB).
// Round-3 single-barrier double-buffered K/V staging. O written tiled.
// ---------------------------------------------------------------------------
__global__ __launch_bounds__(256)
void attn_kernel(const unsigned short* __restrict__ Q, const unsigned short* __restrict__ K,
                 const unsigned short* __restrict__ VT, unsigned short* __restrict__ O) {
    __shared__ unsigned short Kb[2][64][72];   // [buf][key][dk]
    __shared__ unsigned short Vb[2][64][72];   // [buf][dk][key]
    __shared__ unsigned short Ps[4][16][72];   // per-wave P round-trip
    const int t = threadIdx.x;
    const int w = t >> 6, lane = t & 63, quad = lane >> 4, l15 = lane & 15;

    const int idx = blockIdx.x;
    const int xcd = idx & 7;
    const int j   = idx >> 3;                  // 0..95
    const int bh  = xcd + 8 * (j >> 4);        // 0..47
    const int s   = j & 15;                    // pair index
    const int sA  = s, sB = 31 - s;
    const int q0A = sA * 64, q0B = sB * 64;
    const int nkt = sB + 1;
    const size_t kvbase = (size_t)bh * SEQ * DK;

    // persistent Q A-frags for both strips (16 rows per wave each)
    v8s qfA[2], qfB[2];
    #pragma unroll
    for (int c = 0; c < 2; ++c) {
        qfA[c] = *(const v8s*)(Q + kvbase + (size_t)(q0A + w * 16 + l15) * DK + c * 32 + quad * 8);
        qfB[c] = *(const v8s*)(Q + kvbase + (size_t)(q0B + w * 16 + l15) * DK + c * 32 + quad * 8);
    }

    v4f oA[4], oB[4];
    #pragma unroll
    for (int nf = 0; nf < 4; ++nf) { oA[nf] = (v4f){0,0,0,0}; oB[nf] = (v4f){0,0,0,0}; }
    float lsA[4] = {0,0,0,0}, lsB[4] = {0,0,0,0};

    const int srow = t >> 3;          // 0..31
    const int scol = (t & 7) * 8;     // 0..56

    // preload tile 0
    v8s kr0 = *(const v8s*)(K  + kvbase + (size_t)srow * DK + scol);
    v8s kr1 = *(const v8s*)(K  + kvbase + (size_t)(srow + 32) * DK + scol);
    v8s vr0 = *(const v8s*)(VT + kvbase + ((size_t)srow << 11) + scol);
    v8s vr1 = *(const v8s*)(VT + kvbase + ((size_t)(srow + 32) << 11) + scol);
    *(v8s*)&Kb[0][srow][scol]      = kr0;
    *(v8s*)&Kb[0][srow + 32][scol] = kr1;
    *(v8s*)&Vb[0][srow][scol]      = vr0;
    *(v8s*)&Vb[0][srow + 32][scol] = vr1;
    __syncthreads();

    const int rA = q0A + w * 16 + quad * 4;    // mask base rows
    const int rB = q0B + w * 16 + quad * 4;

    for (int kt = 0; kt < nkt; ++kt) {
        const int k0 = kt * 64;
        const int cur = kt & 1;
        // prefetch next tile into regs
        if (kt + 1 < nkt) {
            const int kn = k0 + 64;
            kr0 = *(const v8s*)(K  + kvbase + (size_t)(kn + srow) * DK + scol);
            kr1 = *(const v8s*)(K  + kvbase + (size_t)(kn + srow + 32) * DK + scol);
            vr0 = *(const v8s*)(VT + kvbase + ((size_t)srow << 11) + kn + scol);
            vr1 = *(const v8s*)(VT + kvbase + ((size_t)(srow + 32) << 11) + kn + scol);
        }

        // ---- strip B (always active) ----
        {
            v4f sc[4];
            #pragma unroll
            for (int s4 = 0; s4 < 4; ++s4) sc[s4] = (v4f){0,0,0,0};
            #pragma unroll
            for (int c = 0; c < 2; ++c)
                #pragma unroll
                for (int s4 = 0; s4 < 4; ++s4) {
                    const v8s kf = *(const v8s*)&Kb[cur][s4 * 16 + l15][c * 32 + quad * 8];
                    sc[s4] = __builtin_amdgcn_mfma_f32_16x16x32_bf16(qfB[c], kf, sc[s4], 0, 0, 0);
                }
            if (kt < nkt - 1) {
                #pragma unroll
                for (int s4 = 0; s4 < 4; ++s4)
                    #pragma unroll
                    for (int r = 0; r < 4; ++r) {
                        const float p = __expf(sc[s4][r]);
                        lsB[r] += p;
                        Ps[w][quad * 4 + r][s4 * 16 + l15] = f2bf_trunc(p);
                    }
            } else {
                #pragma unroll
                for (int s4 = 0; s4 < 4; ++s4) {
                    const int key = k0 + s4 * 16 + l15;
                    #pragma unroll
                    for (int r = 0; r < 4; ++r) {
                        const float p = (key <= rB + r) ? __expf(sc[s4][r]) : 0.f;
                        lsB[r] += p;
                        Ps[w][quad * 4 + r][s4 * 16 + l15] = f2bf_trunc(p);
                    }
                }
            }
            #pragma unroll
            for (int kc = 0; kc < 2; ++kc) {
                const v8s pf = *(const v8s*)&Ps[w][l15][kc * 32 + quad * 8];
                #pragma unroll
                for (int nf = 0; nf < 4; ++nf) {
                    const v8s vf = *(const v8s*)&Vb[cur][nf * 16 + l15][kc * 32 + quad * 8];
                    oB[nf] = __builtin_amdgcn_mfma_f32_16x16x32_bf16(pf, vf, oB[nf], 0, 0, 0);
                }
            }
        }

        // ---- strip A (active while kt <= sA) ----
        if (kt <= sA) {
            v4f sc[4];
            #pragma unroll
            for (int s4 = 0; s4 < 4; ++s4) sc[s4] = (v4f){0,0,0,0};
            #pragma unroll
            for (int c = 0; c < 2; ++c)
                #pragma unroll
                for (int s4 = 0; s4 < 4; ++s4) {
                    const v8s kf = *(const v8s*)&Kb[cur][s4 * 16 + l15][c * 32 + quad * 8];
                    sc[s4] = __builtin_amdgcn_mfma_f32_16x16x32_bf16(qfA[c], kf, sc[s4], 0, 0, 0);
                }
            if (kt < sA) {
                #pragma unroll
                for (int s4 = 0; s4 < 4; ++s4)
                    #pragma unroll
                    for (int r = 0; r < 4; ++r) {
                        const float p = __expf(sc[s4][r]);
                        lsA[r] += p;
                        Ps[w][quad * 4 + r][s4 * 16 + l15] = f2bf_trunc(p);
                    }
            } else {
                #pragma unroll
                for (int s4 = 0; s4 < 4; ++s4) {
                    const int key = k0 + s4 * 16 + l15;
                    #pragma unroll
                    for (int r = 0; r < 4; ++r) {
                        const float p = (key <= rA + r) ? __expf(sc[s4][r]) : 0.f;
                        lsA[r] += p;
                        Ps[w][quad * 4 + r][s4 * 16 + l15] = f2bf_trunc(p);
                    }
                }
            }
            #pragma unroll
            for (int kc = 0; kc < 2; ++kc) {
                const v8s pf = *(const v8s*)&Ps[w][l15][kc * 32 + quad * 8];
                #pragma unroll
                for (int nf = 0; nf < 4; ++nf) {
                    const v8s vf = *(const v8s*)&Vb[cur][nf * 16 + l15][kc * 32 + quad * 8];
                    oA[nf] = __builtin_amdgcn_mfma_f32_16x16x32_bf16(pf, vf, oA[nf], 0, 0, 0);
                }
            }
        }

        // store prefetched tile into the other buffer, then one barrier
        if (kt + 1 < nkt) {
            const int nxt = 1 - cur;
            *(v8s*)&Kb[nxt][srow][scol]      = kr0;
            *(v8s*)&Kb[nxt][srow + 32][scol] = kr1;
            *(v8s*)&Vb[nxt][srow][scol]      = vr0;
            *(v8s*)&Vb[nxt][srow + 32][scol] = vr1;
        }
        __syncthreads();
    }

    // row-sum reductions across the 16 lanes holding each row
    #pragma unroll
    for (int off = 1; off < 16; off <<= 1)
        #pragma unroll
        for (int r = 0; r < 4; ++r) {
            lsA[r] += __shfl_xor(lsA[r], off);
            lsB[r] += __shfl_xor(lsB[r], off);
        }

    // tiled O writes: brick = (b*16 + row>>7)*12 + h
    const int b = bh / HEADS, h = bh % HEADS;
    const size_t brA = ((size_t)(b * 16 + (q0A >> 7)) * KT + h) * BRICK;
    const size_t brB = ((size_t)(b * 16 + (q0B >> 7)) * KT + h) * BRICK;
    #pragma unroll
    for (int r = 0; r < 4; ++r) {
        const float invA = 1.f / lsA[r];
        const float invB = 1.f / lsB[r];
        const int rowlA = (q0A & 127) + w * 16 + quad * 4 + r;
        const int rowlB = (q0B & 127) + w * 16 + quad * 4 + r;
        #pragma unroll
        for (int nf = 0; nf < 4; ++nf) {
            O[brA + (size_t)rowlA * 64 + nf * 16 + l15] = f2bf(oA[nf][r] * invA);
            O[brB + (size_t)rowlB * 64 + nf * 16 + l15] = f2bf(oB[nf][r] * invB);
        }
    }
}

extern "C" void kernel_launch(void* const* d_in, const int* in_sizes, int n_in,
                              void* d_out, int out_size, void* d_ws, size_t ws_size,
                              hipStream_t stream) {
    const float* x  = (const float*)d_in[0];
    const float* Wq = (const float*)d_in[1];
    const float* bq = (const float*)d_in[2];
    const float* Wk = (const float*)d_in[3];
    const float* bk = (const float*)d_in[4];
    const float* Wv = (const float*)d_in[5];
    const float* bv = (const float*)d_in[6];
    const float* Wo = (const float*)d_in[7];
    const float* bo = (const float*)d_in[8];
    float* out = (float*)d_out;

    unsigned short* xb  = (unsigned short*)d_ws;      // tiled [8192][768] bf16; reused as ob
    unsigned short* qb  = xb  + NE;                   // [bh][s][64]
    unsigned short* kb  = qb  + NE;                   // [bh][s][64]
    unsigned short* vtb = kb  + NE;                   // [bh][64][s]
    unsigned short* wt  = vtb + NE;                   // 4 x [768][768] bf16 tiled (q,k,v,o)
    unsigned short* ob  = xb;                         // alias (xb dead after gemm_qkv)

    cvt_x_kernel<<<dim3(NE / (8 * 256)), 256, 0, stream>>>(x, xb);
    cvt_w_kernel<<<dim3(12, 12, 4), 256, 0, stream>>>(Wq, Wk, Wv, Wo, wt);
    gemm_qkv_kernel<<<dim3(64, 6, 3), 256, 0, stream>>>(xb, wt, bq, bk, bv, qb, kb, vtb);
    attn_kernel<<<dim3(768), 256, 0, stream>>>(qb, kb, vtb, ob);
    gemm_out_kernel<<<dim3(64, 6), 256, 0, stream>>>(ob, wt + (size_t)3 * DM * DM, bo, out);
}